// Round 5
// baseline (248.475 us; speedup 1.0000x reference)
//
#include <hip/hip_runtime.h>

typedef __attribute__((ext_vector_type(4))) float f32x4;
typedef __attribute__((ext_vector_type(8))) short bf16x8;

__device__ __forceinline__ short f2bf(float f) {
    union { float f; unsigned u; } v; v.f = f;
    unsigned u = v.u + 0x7FFFu + ((v.u >> 16) & 1u);   // RNE
    return (short)(u >> 16);
}
__device__ __forceinline__ int pack_bf2(float a, float b) {
    union { float f; unsigned u; } ua, ub; ua.f = a; ub.f = b;
    unsigned x = ua.u + 0x8000u, y = ub.u + 0x8000u;   // round half-up
    return (int)__builtin_amdgcn_perm(y, x, 0x07060302u);
}
__device__ __forceinline__ float bflo(int p) {
    union { int i; float f; } v; v.i = p << 16; return v.f;
}
__device__ __forceinline__ float bfhi(int p) {
    union { int i; float f; } v; v.i = p & 0xffff0000; return v.f;
}

// ---------------------------------------------------------------------------
// Prep (16 blocks x 256) — UNCHANGED from R4 (verified absmax 1.0).
//  AbP16: per c, frag f=(rt*2+kc)*64+L holds A_c[pi(rt*16+(L&15))][32kc+8(L>>4)+j]
//  Bb16 : bias GEMV A-op, rows=comps: -2*(A_c m_c)
//  kscal: m^T A m
// ---------------------------------------------------------------------------
__global__ void gmm_prep(const float* __restrict__ Ainv,
                         const float* __restrict__ means,
                         short* __restrict__ AbP16,
                         short* __restrict__ Bb16,
                         float* __restrict__ kscal) {
    __shared__ float sA[64 * 68];
    __shared__ float sm[64];
    __shared__ float sb[64];
    const int c = blockIdx.x, t = threadIdx.x;
    const float* A = Ainv + c * 4096;
    #pragma unroll
    for (int i = 0; i < 4; ++i) {
        int flat = i * 1024 + t * 4;
        int r = flat >> 6, col = flat & 63;
        *(f32x4*)&sA[r * 68 + col] = *(const f32x4*)(A + flat);
    }
    if (t < 64) sm[t] = means[c * 64 + t];
    __syncthreads();
    {   // b[j] = A[j,:].m  (4 lanes per row)
        int j = t >> 2, seg = t & 3;
        float p = 0.f;
        #pragma unroll
        for (int k = 0; k < 16; ++k) p += sA[j * 68 + seg * 16 + k] * sm[seg * 16 + k];
        p += __shfl_xor(p, 1, 64); p += __shfl_xor(p, 2, 64);
        if ((t & 3) == 0) sb[j] = p;
    }
    __syncthreads();
    if (t < 64) {
        float km = sm[t] * sb[t];
        #pragma unroll
        for (int off = 32; off >= 1; off >>= 1) km += __shfl_xor(km, off, 64);
        if (t == 0) kscal[c] = km;
    }
    #pragma unroll
    for (int rep = 0; rep < 2; ++rep) {     // permuted A fragments
        int f = rep * 256 + t;
        int rt = f >> 7, kc = (f >> 6) & 1, L = f & 63;
        int ln = L & 15, q = L >> 4;
        int pj = (rt >> 1) * 32 + 8 * (ln >> 2) + 4 * (rt & 1) + (ln & 3);
        const float* src = &sA[pj * 68 + 32 * kc + 8 * q];
        bf16x8 v;
        #pragma unroll
        for (int j = 0; j < 8; ++j) v[j] = f2bf(src[j]);
        *(bf16x8*)(AbP16 + c * 4096 + f * 8) = v;
    }
    if (t < 8) {                            // bias GEMV frags (row = comp c)
        int kc = t >> 2, q = t & 3, L = q * 16 + c;
        bf16x8 v;
        #pragma unroll
        for (int j = 0; j < 8; ++j) v[j] = f2bf(-2.f * sb[32 * kc + 8 * q + j]);
        *(bf16x8*)(Bb16 + kc * 512 + L * 8) = v;
    }
}

union BFrag { bf16x8 v; int i[4]; };

// process 8 components resident in sAb (comp base = 8*H), fully unrolled so
// all lin[t][c&3] selections are compile-time registers.
template<int H>
__device__ __forceinline__ void process_half(
    const short* __restrict__ sAb, const BFrag (&xb)[4][2],
    const f32x4 (&lin)[4], const f32x4 wc4, float (&slog)[4],
    int lane, int q) {
    const f32x4 zero4 = {0.f, 0.f, 0.f, 0.f};
    #pragma unroll
    for (int cl = 0; cl < 8; ++cl) {
        bf16x8 af[8];                       // frag f = rt*2+kc
        #pragma unroll
        for (int f = 0; f < 8; ++f)
            af[f] = *(const bf16x8*)&sAb[cl * 4096 + f * 512 + lane * 8];
        const int c = H * 8 + cl;
        #pragma unroll
        for (int t = 0; t < 4; ++t) {
            float dp = 0.f;
            #pragma unroll
            for (int rt = 0; rt < 4; ++rt) {
                f32x4 acc = __builtin_amdgcn_mfma_f32_16x16x32_bf16(
                    af[rt * 2 + 0], xb[t][0].v, zero4, 0, 0, 0);
                acc = __builtin_amdgcn_mfma_f32_16x16x32_bf16(
                    af[rt * 2 + 1], xb[t][1].v, acc, 0, 0, 0);
                int pa = xb[t][rt >> 1].i[(rt & 1) * 2];
                int pb = xb[t][rt >> 1].i[(rt & 1) * 2 + 1];
                dp += acc[0] * bflo(pa) + acc[1] * bfhi(pa)
                    + acc[2] * bflo(pb) + acc[3] * bfhi(pb);
            }
            dp += __shfl_xor(dp, 16, 64);
            dp += __shfl_xor(dp, 32, 64);
            if (q == (c >> 2)) {            // owner quad accumulates
                float d = fmaxf(dp + lin[t][c & 3], 1e-30f);
                slog[t] = fmaf(wc4[c & 3], __builtin_amdgcn_logf(d), slog[t]);
            }
        }
    }
}

// ---------------------------------------------------------------------------
// Main (512 blocks x 512 threads): 8 waves x 64 samples, x packed bf16 in
// registers for the whole kernel; A-frags resident in LDS in two 64 KB
// halves (8 comps each); 3 barriers total. Linear+const via bias GEMV with
// kscal folded into C-init.
// ---------------------------------------------------------------------------
__global__ __launch_bounds__(512, 2) void gmm_main(
    const float* __restrict__ X,
    const float* __restrict__ weights,
    const short* __restrict__ AbP16,
    const short* __restrict__ Bb16,
    const float* __restrict__ kscal,
    float* __restrict__ out) {

    __shared__ short sAb[32768];            // 64 KB: 8 comps x 8 KB

    const int tid = threadIdx.x;
    const int lane = tid & 63, w = tid >> 6;
    const int q = lane >> 4, ln = lane & 15;
    const int base = blockIdx.x * 512 + w * 64;

    // ---- x -> fp32 regs (16 f32x4), issued first so HBM latency overlaps ----
    f32x4 xv[4][4];                         // [t][kc*2+half]
    #pragma unroll
    for (int t = 0; t < 4; ++t) {
        const float* xr = X + (size_t)(base + t * 16 + ln) * 64 + 8 * q;
        #pragma unroll
        for (int kc = 0; kc < 2; ++kc) {
            xv[t][kc * 2]     = *(const f32x4*)(xr + 32 * kc);
            xv[t][kc * 2 + 1] = *(const f32x4*)(xr + 32 * kc + 4);
        }
    }

    // ---- half-0 A-frag staging loads ----
    int4 pf[8];
    #pragma unroll
    for (int i = 0; i < 8; ++i)
        pf[i] = ((const int4*)AbP16)[i * 512 + tid];

    // ---- constants ----
    f32x4 kw  = *(const f32x4*)(kscal + 4 * q);
    f32x4 wc4 = *(const f32x4*)(weights + 4 * q);
    bf16x8 bb0 = *(const bf16x8*)(Bb16 + lane * 8);
    bf16x8 bb1 = *(const bf16x8*)(Bb16 + 512 + lane * 8);

    // ---- pack x to bf16 B-frags (computed values: cannot rematerialize) ----
    BFrag xb[4][2];
    #pragma unroll
    for (int t = 0; t < 4; ++t)
        #pragma unroll
        for (int kc = 0; kc < 2; ++kc) {
            xb[t][kc].i[0] = pack_bf2(xv[t][kc * 2][0], xv[t][kc * 2][1]);
            xb[t][kc].i[1] = pack_bf2(xv[t][kc * 2][2], xv[t][kc * 2][3]);
            xb[t][kc].i[2] = pack_bf2(xv[t][kc * 2 + 1][0], xv[t][kc * 2 + 1][1]);
            xb[t][kc].i[3] = pack_bf2(xv[t][kc * 2 + 1][2], xv[t][kc * 2 + 1][3]);
        }

    // ---- lin[t][r] = kscal[4q+r] - 2 b_{4q+r}.x_n   (bias GEMV) ----
    f32x4 lin[4];
    #pragma unroll
    for (int t = 0; t < 4; ++t) {
        lin[t] = __builtin_amdgcn_mfma_f32_16x16x32_bf16(bb0, xb[t][0].v, kw, 0, 0, 0);
        lin[t] = __builtin_amdgcn_mfma_f32_16x16x32_bf16(bb1, xb[t][1].v, lin[t], 0, 0, 0);
    }

    // ---- stage half 0 ----
    #pragma unroll
    for (int i = 0; i < 8; ++i)
        ((int4*)sAb)[i * 512 + tid] = pf[i];
    __syncthreads();

    // ---- prefetch half 1 while computing half 0 ----
    #pragma unroll
    for (int i = 0; i < 8; ++i)
        pf[i] = ((const int4*)AbP16)[4096 + i * 512 + tid];

    float slog[4] = {0.f, 0.f, 0.f, 0.f};
    process_half<0>(sAb, xb, lin, wc4, slog, lane, q);

    __syncthreads();
    #pragma unroll
    for (int i = 0; i < 8; ++i)
        ((int4*)sAb)[i * 512 + tid] = pf[i];
    __syncthreads();

    process_half<1>(sAb, xb, lin, wc4, slog, lane, q);

    // ---- combine quads, write ----
    #pragma unroll
    for (int t = 0; t < 4; ++t) {
        float tot = slog[t];
        tot += __shfl_xor(tot, 16, 64);
        tot += __shfl_xor(tot, 32, 64);
        if (q == 0) out[base + t * 16 + ln] = __builtin_amdgcn_exp2f(tot);
    }
}

extern "C" void kernel_launch(void* const* d_in, const int* in_sizes, int n_in,
                              void* d_out, int out_size, void* d_ws, size_t ws_size,
                              hipStream_t stream) {
    const float* X       = (const float*)d_in[0];
    const float* Ainv    = (const float*)d_in[1];
    const float* means   = (const float*)d_in[2];
    const float* weights = (const float*)d_in[3];
    float* out = (float*)d_out;
    const int N = in_sizes[0] / 64;

    short* AbP16 = (short*)d_ws;                       // 131072 B
    short* Bb16  = (short*)((char*)d_ws + 131072);     // 2048 B
    float* kscal = (float*)((char*)d_ws + 133120);     // 64 B

    gmm_prep<<<dim3(16), dim3(256), 0, stream>>>(Ainv, means, AbP16, Bb16, kscal);
    gmm_main<<<dim3(N / 512), dim3(512), 0, stream>>>(X, weights, AbP16, Bb16, kscal, out);
}

// Round 6
// 132.355 us; speedup vs baseline: 1.8773x; 1.8773x over previous
//
#include <hip/hip_runtime.h>

typedef __attribute__((ext_vector_type(4))) float f32x4;
typedef __attribute__((ext_vector_type(8))) short bf16x8;

__device__ __forceinline__ short f2bf(float f) {
    union { float f; unsigned u; } v; v.f = f;
    unsigned u = v.u + 0x7FFFu + ((v.u >> 16) & 1u);   // RNE
    return (short)(u >> 16);
}
__device__ __forceinline__ int pack_bf2(float a, float b) {
    union { float f; unsigned u; } ua, ub; ua.f = a; ub.f = b;
    unsigned x = ua.u + 0x8000u, y = ub.u + 0x8000u;   // round half-up
    return (int)__builtin_amdgcn_perm(y, x, 0x07060302u);
}
__device__ __forceinline__ float bflo(int p) {
    union { int i; float f; } v; v.i = p << 16; return v.f;
}
__device__ __forceinline__ float bfhi(int p) {
    union { int i; float f; } v; v.i = p & 0xffff0000; return v.f;
}

// ---------------------------------------------------------------------------
// Prep (16 blocks x 256):
//  AbP16: per c, frag f=(rt*2+kc)*64+L holds A_c[pi(rt*16+(L&15))][32kc+8(L>>4)+j]
//  biasP: fp32, row-permuted: biasP[c][p] = -2*(A_c m_c)[pi(p)]  (C-init term)
//  kscal: m^T A m
// ---------------------------------------------------------------------------
__global__ void gmm_prep(const float* __restrict__ Ainv,
                         const float* __restrict__ means,
                         short* __restrict__ AbP16,
                         float* __restrict__ biasP,
                         float* __restrict__ kscal) {
    __shared__ float sA[64 * 68];
    __shared__ float sm[64];
    __shared__ float sb[64];
    const int c = blockIdx.x, t = threadIdx.x;
    const float* A = Ainv + c * 4096;
    #pragma unroll
    for (int i = 0; i < 4; ++i) {
        int flat = i * 1024 + t * 4;
        int r = flat >> 6, col = flat & 63;
        *(f32x4*)&sA[r * 68 + col] = *(const f32x4*)(A + flat);
    }
    if (t < 64) sm[t] = means[c * 64 + t];
    __syncthreads();
    {   // b[j] = A[j,:].m  (4 lanes per row)
        int j = t >> 2, seg = t & 3;
        float p = 0.f;
        #pragma unroll
        for (int k = 0; k < 16; ++k) p += sA[j * 68 + seg * 16 + k] * sm[seg * 16 + k];
        p += __shfl_xor(p, 1, 64); p += __shfl_xor(p, 2, 64);
        if ((t & 3) == 0) sb[j] = p;
    }
    __syncthreads();
    if (t < 64) {
        float km = sm[t] * sb[t];
        #pragma unroll
        for (int off = 32; off >= 1; off >>= 1) km += __shfl_xor(km, off, 64);
        if (t == 0) kscal[c] = km;
        int rt = t >> 4, qh = (t >> 2) & 3, r = t & 3;
        int pj = (rt >> 1) * 32 + 8 * qh + 4 * (rt & 1) + r;
        biasP[c * 64 + t] = -2.f * sb[pj];
    }
    #pragma unroll
    for (int rep = 0; rep < 2; ++rep) {     // permuted A fragments
        int f = rep * 256 + t;
        int rt = f >> 7, kc = (f >> 6) & 1, L = f & 63;
        int ln = L & 15, q = L >> 4;
        int pj = (rt >> 1) * 32 + 8 * (ln >> 2) + 4 * (rt & 1) + (ln & 3);
        const float* src = &sA[pj * 68 + 32 * kc + 8 * q];
        bf16x8 v;
        #pragma unroll
        for (int j = 0; j < 8; ++j) v[j] = f2bf(src[j]);
        *(bf16x8*)(AbP16 + c * 4096 + f * 8) = v;
    }
}

union BFrag { bf16x8 v; int i[4]; };

// ---------------------------------------------------------------------------
// Main (1024 blocks x 256): 4 waves x 64 samples; x packed bf16 persistent in
// regs (32 VGPRs). A staged in LDS 4 comps at a time (32 KB, 4 stages); per
// comp 8 ds_read_b128 amortized over 4 tiles. Linear term in MFMA C-init
// (bias rows, fp32 from LDS); kscal/w via dynamic-LDS broadcast; every lane
// accumulates full slog (no quad ownership, no final reduce).
// ---------------------------------------------------------------------------
__global__ __launch_bounds__(256) void gmm_main(
    const float* __restrict__ X,
    const float* __restrict__ weights,
    const short* __restrict__ AbP16,
    const float* __restrict__ biasP,
    const float* __restrict__ kscal,
    float* __restrict__ out) {

    __shared__ short sAb[16384];          // 32 KB: 4 comps x 8 KB
    __shared__ float sBias[16 * 64];      // 4 KB, permuted rows
    __shared__ float sKW[32];             // [0..15]=kscal, [16..31]=w

    const int tid = threadIdx.x;
    const int lane = tid & 63, w = tid >> 6;
    const int q = lane >> 4, ln = lane & 15;
    const int base = blockIdx.x * 256 + w * 64;

    // stage 0 A-frags + bias + kw
    #pragma unroll
    for (int i = 0; i < 8; ++i)
        ((int4*)sAb)[i * 256 + tid] = ((const int4*)AbP16)[i * 256 + tid];
    ((f32x4*)sBias)[tid] = ((const f32x4*)biasP)[tid];
    if (tid < 16) { sKW[tid] = kscal[tid]; sKW[16 + tid] = weights[tid]; }

    // x -> persistent packed bf16 B-frags (transient fp32 per tile)
    BFrag xb[4][2];
    #pragma unroll
    for (int t = 0; t < 4; ++t) {
        const float* xr = X + (size_t)(base + t * 16 + ln) * 64 + 8 * q;
        #pragma unroll
        for (int kc = 0; kc < 2; ++kc) {
            f32x4 a = *(const f32x4*)(xr + 32 * kc);
            f32x4 b = *(const f32x4*)(xr + 32 * kc + 4);
            xb[t][kc].i[0] = pack_bf2(a[0], a[1]);
            xb[t][kc].i[1] = pack_bf2(a[2], a[3]);
            xb[t][kc].i[2] = pack_bf2(b[0], b[1]);
            xb[t][kc].i[3] = pack_bf2(b[2], b[3]);
        }
    }
    __syncthreads();

    float slog[4] = {0.f, 0.f, 0.f, 0.f};

    #pragma unroll 1
    for (int g = 0; g < 4; ++g) {
        #pragma unroll 1
        for (int cl = 0; cl < 4; ++cl) {
            const int c = g * 4 + cl;
            bf16x8 af[8];
            #pragma unroll
            for (int f = 0; f < 8; ++f)
                af[f] = *(const bf16x8*)&sAb[cl * 4096 + f * 512 + lane * 8];
            f32x4 bias[4];
            #pragma unroll
            for (int rt = 0; rt < 4; ++rt)
                bias[rt] = *(const f32x4*)&sBias[c * 64 + rt * 16 + q * 4];
            const float kc_ = sKW[c], wcc = sKW[16 + c];

            #pragma unroll
            for (int t = 0; t < 4; ++t) {
                float dp = 0.f;
                #pragma unroll
                for (int rt = 0; rt < 4; ++rt) {
                    f32x4 acc = __builtin_amdgcn_mfma_f32_16x16x32_bf16(
                        af[rt * 2 + 0], xb[t][0].v, bias[rt], 0, 0, 0);
                    acc = __builtin_amdgcn_mfma_f32_16x16x32_bf16(
                        af[rt * 2 + 1], xb[t][1].v, acc, 0, 0, 0);
                    int pa = xb[t][rt >> 1].i[(rt & 1) * 2];
                    int pb = xb[t][rt >> 1].i[(rt & 1) * 2 + 1];
                    dp += acc[0] * bflo(pa) + acc[1] * bfhi(pa)
                        + acc[2] * bflo(pb) + acc[3] * bfhi(pb);
                }
                dp += __shfl_xor(dp, 16, 64);
                dp += __shfl_xor(dp, 32, 64);
                float d = fmaxf(dp + kc_, 1e-30f);
                slog[t] = fmaf(wcc, __builtin_amdgcn_logf(d), slog[t]);
            }
        }
        if (g < 3) {                      // restage next 4 comps
            __syncthreads();
            const int4* src = (const int4*)(AbP16 + (g + 1) * 16384);
            #pragma unroll
            for (int i = 0; i < 8; ++i)
                ((int4*)sAb)[i * 256 + tid] = src[i * 256 + tid];
            __syncthreads();
        }
    }

    if (q == 0) {
        #pragma unroll
        for (int t = 0; t < 4; ++t)
            out[base + t * 16 + ln] = __builtin_amdgcn_exp2f(slog[t]);
    }
}

extern "C" void kernel_launch(void* const* d_in, const int* in_sizes, int n_in,
                              void* d_out, int out_size, void* d_ws, size_t ws_size,
                              hipStream_t stream) {
    const float* X       = (const float*)d_in[0];
    const float* Ainv    = (const float*)d_in[1];
    const float* means   = (const float*)d_in[2];
    const float* weights = (const float*)d_in[3];
    float* out = (float*)d_out;
    const int N = in_sizes[0] / 64;

    short* AbP16 = (short*)d_ws;                       // 131072 B
    float* biasP = (float*)((char*)d_ws + 131072);     // 4096 B
    float* kscal = (float*)((char*)d_ws + 135168);     // 64 B

    gmm_prep<<<dim3(16), dim3(256), 0, stream>>>(Ainv, means, AbP16, biasP, kscal);
    gmm_main<<<dim3(N / 256), dim3(256), 0, stream>>>(X, weights, AbP16, biasP, kscal, out);
}